// Round 5
// baseline (160.187 us; speedup 1.0000x reference)
//
#include <hip/hip_runtime.h>
#include <hip/hip_bf16.h>
#include <cstdint>

#define N_PTS 8192
#define DIM 128
#define NBLOCKS 4160  // sum over tI of (128 - 2*tI): 128x64 upper-triangle tiles

typedef __attribute__((ext_vector_type(8))) __bf16 bf16x8;
typedef __attribute__((ext_vector_type(4))) float f32x4;

// base-2 logit constants: l2 = l/ln2
#define K_A 369.32995f  // 256/ln2
#define K_B 738.65990f  // 512/ln2
#define K_C 346.24683f  // 240/ln2
#define K_D 23.083122f  // 16/ln2
#define LN2 0.69314718f

// lp2(s) = (256 s^2 - 512 s + 240)/ln2, monotone decreasing for s < 1
__device__ __forceinline__ float lp2_of(float s) {
  return __builtin_fmaf(s, __builtin_fmaf(s, K_A, -K_B), K_C);
}
// base-2 lse merge: s <- s*2^(m-mm) + s2*2^(m2-mm)
__device__ __forceinline__ void lse_merge2(float& m, float& s, float m2, float s2) {
  const float mm = fmaxf(m, m2);
  s = __builtin_fmaf(s, __builtin_amdgcn_exp2f(m - mm),
                     s2 * __builtin_amdgcn_exp2f(m2 - mm));
  m = mm;
}

// RNE float -> bf16 bits (inputs finite)
__device__ __forceinline__ unsigned short f2bf(float x) {
  unsigned int u = __float_as_uint(x);
  return (unsigned short)((u + 0x7FFFu + ((u >> 16) & 1u)) >> 16);
}

// One wave per row: L2-normalize (eps=1e-12), store bf16 bits; zero counter.
__global__ __launch_bounds__(256) void normalize_kernel(const float* __restrict__ feat,
                                                        unsigned short* __restrict__ fb,
                                                        int* __restrict__ counter) {
  if (blockIdx.x == 0 && threadIdx.x == 0) *counter = 0;
  const int row = blockIdx.x * 4 + (threadIdx.x >> 6);
  const int lane = threadIdx.x & 63;
  const float2 v = *(const float2*)(feat + row * DIM + lane * 2);
  float ss = v.x * v.x + v.y * v.y;
#pragma unroll
  for (int o = 32; o > 0; o >>= 1) ss += __shfl_xor(ss, o);
  const float inv = 1.0f / fmaxf(sqrtf(ss), 1e-12f);
  const unsigned int pack =
      (unsigned int)f2bf(v.x * inv) | ((unsigned int)f2bf(v.y * inv) << 16);
  *(unsigned int*)(fb + row * DIM + lane * 2) = pack;
}

// Two-pass epilogue over 16 elements/thread. Pass1: raw-sim extremes + eqmask
// (no logits, no exp). Pass2: one exp2 per element. acc is only 16 VGPRs, so
// keeping it live across the block reduction is cheap (no spill at 128-reg cap).
template <bool DIAG>
__device__ __forceinline__ void epilogue(const f32x4 (&acc)[2][2], const int4 (&liv)[2],
                                         const int (&lj)[2], int dj, int lane, int wave,
                                         int t, int k, float* redA, float* redB,
                                         float4* __restrict__ partials,
                                         int* __restrict__ counter, int* lastflag) {
  // ---- pass 1 ----
  float minP = 1e30f, cN = 0.f;
  unsigned int eqm = 0;
#pragma unroll
  for (int tm = 0; tm < 2; ++tm) {
    const int li[4] = {liv[tm].x, liv[tm].y, liv[tm].z, liv[tm].w};
#pragma unroll
    for (int tn = 0; tn < 2; ++tn) {
#pragma unroll
      for (int r = 0; r < 4; ++r) {
        const float s = acc[tm][tn][r];
        const bool eq = (li[r] == lj[tn]);
        eqm |= (eq ? 1u : 0u) << (((tm * 2 + tn) << 2) + r);
        bool pm = eq, nm = !eq;
        if (DIAG) {
          const bool valid = (dj + tn * 16 - tm * 16 - r) > 0;
          pm = pm && valid;
          nm = nm && valid;
        }
        minP = fminf(minP, pm ? s : 1e30f);
        const float u = fmaxf(s, -0.25f);
        cN = fmaxf(cN, nm ? fabsf(u) : 0.f);
      }
    }
  }
#pragma unroll
  for (int o = 32; o > 0; o >>= 1) {
    minP = fminf(minP, __shfl_xor(minP, o));
    cN = fmaxf(cN, __shfl_xor(cN, o));
  }
  if (lane == 0) { redA[wave] = minP; redB[wave] = cN; }
  __syncthreads();
  float bm = 1e30f, bc = 0.f;
#pragma unroll
  for (int w = 0; w < 8; ++w) {
    bm = fminf(bm, redA[w]);
    bc = fmaxf(bc, redB[w]);
  }
  // Block stream maxima (base-2). Empty pos -> lp2_of(1e30) huge -> exp2(-huge)=0.
  // Diag-invalid eq elements may overflow exp2 to inf in pass 2; the select
  // masks them before accumulation (verified absmax 0 in round 4).
  const float Mp2 = lp2_of(bm);
  const float Mn2 = __builtin_fmaf(bc * bc, K_A, -K_D);
  __syncthreads();  // redA/redB reuse

  // ---- pass 2 ----
  float spA[4] = {0.f, 0.f, 0.f, 0.f}, snA[4] = {0.f, 0.f, 0.f, 0.f};
#pragma unroll
  for (int tm = 0; tm < 2; ++tm) {
#pragma unroll
    for (int tn = 0; tn < 2; ++tn) {
      const int vbase = DIAG ? (dj + tn * 16 - tm * 16) : 0;
#pragma unroll
      for (int r = 0; r < 4; ++r) {
        const float s = acc[tm][tn][r];
        const bool eq = (eqm & (1u << (((tm * 2 + tn) << 2) + r))) != 0u;
        const float lP = lp2_of(s);
        const float u = fmaxf(s, -0.25f);
        const float lN = __builtin_fmaf(u * u, K_A, -K_D);
        const float l = eq ? lP : lN;
        const float m = eq ? Mp2 : Mn2;
        float e = __builtin_amdgcn_exp2f(l - m);
        if (DIAG) e = (vbase > r) ? e : 0.f;
        const float ep = eq ? e : 0.f;
        spA[r] += ep;
        snA[r] += e - ep;
      }
    }
  }
  float sp = (spA[0] + spA[1]) + (spA[2] + spA[3]);
  float sn = (snA[0] + snA[1]) + (snA[2] + snA[3]);
#pragma unroll
  for (int o = 32; o > 0; o >>= 1) {
    sp += __shfl_xor(sp, o);
    sn += __shfl_xor(sn, o);
  }
  if (lane == 0) { redA[wave] = sp; redB[wave] = sn; }
  __syncthreads();
  if (t == 0) {
    float Sp = 0.f, Sn = 0.f;
#pragma unroll
    for (int w = 0; w < 8; ++w) { Sp += redA[w]; Sn += redB[w]; }
    partials[k] = make_float4(Sp == 0.f ? -1e30f : Mp2, Sp,
                              Sn == 0.f ? -1e30f : Mn2, Sn);
    __threadfence();
    *lastflag = (atomicAdd(counter, 1) == NBLOCKS - 1);
  }
}

// 128x64 tile per block, 512 threads (8 waves of 32x32), upper-triangle tiles.
// Single-shot K staging: A(32KB)+B(16KB) in LDS, ONE barrier, then a
// barrier-free ds_read/MFMA loop. 48KB LDS -> 2 blocks/CU; 16-reg acc -> no
// spill at the (512,4) 128-reg cap.
__global__ __launch_bounds__(512, 4) void pair_kernel(const unsigned short* __restrict__ f,
                                                      const int* __restrict__ labels,
                                                      float4* __restrict__ partials,
                                                      int* __restrict__ counter,
                                                      float* __restrict__ out) {
  // decode linear block id -> (tI, tJc): F(tI) = tI*(129-tI), tJc in [2*tI, 128)
  const int k = blockIdx.x;
  int tI = (int)((129.0 - sqrt(16641.0 - 4.0 * (double)k)) * 0.5);
  tI = tI < 0 ? 0 : (tI > 63 ? 63 : tI);
  while ((tI + 1) * (128 - tI) <= k) ++tI;
  while (tI * (129 - tI) > k) --tI;
  const int tJc = 2 * tI + (k - tI * (129 - tI));

  __shared__ uint4 sAq[2048];  // 32 KB: 4 slabs of 512 chunks (128 rows x 32 K)
  __shared__ uint4 sBq[1024];  // 16 KB: 4 slabs of 256 chunks (64 rows x 32 K)
  __shared__ float redA[8], redB[8];
  __shared__ float4 fred[8];
  __shared__ int lastflag;

  const int t = threadIdx.x;
  const int lane = t & 63, wave = t >> 6;
  const int wri = wave >> 1, wci = wave & 1;  // 32-row group, 32-col group
  const int rows0 = tI * 128, cols0 = tJc * 64;

  // C/D mapping (16x16x32): col = lane&15, row = (lane>>4)*4 + reg
  const int ibase = rows0 + wri * 32 + (lane >> 4) * 4;
  const int jbase = cols0 + wci * 32 + (lane & 15);
  const int dj = jbase - ibase;

  // label prefetch (latency hides under staging + MFMA)
  int4 liv[2];
  int lj[2];
  liv[0] = *(const int4*)(labels + ibase);
  liv[1] = *(const int4*)(labels + ibase + 16);
  lj[0] = labels[jbase];
  lj[1] = labels[jbase + 16];

  // ---- single-shot staging: chunk c in slab -> row ((c>>6)<<4)|(c&15), k8 (c>>4)&3
  {
    const int rA = ((t >> 6) << 4) | (t & 15);
    const int k8A = ((t >> 4) & 3) * 8;
    const unsigned short* gA = f + (size_t)(rows0 + rA) * DIM + k8A;
#pragma unroll
    for (int kk = 0; kk < 4; ++kk)
      __builtin_amdgcn_global_load_lds(
          (const __attribute__((address_space(1))) unsigned int*)(gA + kk * 32),
          (__attribute__((address_space(3))) unsigned int*)(sAq + kk * 512 + t), 16, 0, 0);
#pragma unroll
    for (int q = 0; q < 2; ++q) {
      const int cb = t + q * 512;
      const int slab = cb >> 8, c2 = cb & 255;
      const int rB = ((c2 >> 6) << 4) | (c2 & 15);
      const int k8B = ((c2 >> 4) & 3) * 8;
      __builtin_amdgcn_global_load_lds(
          (const __attribute__((address_space(1))) unsigned int*)(f +
              (size_t)(cols0 + rB) * DIM + slab * 32 + k8B),
          (__attribute__((address_space(3))) unsigned int*)(sBq + cb), 16, 0, 0);
    }
  }
  __syncthreads();  // the ONLY staging barrier (drains vmcnt)

  f32x4 acc[2][2];
#pragma unroll
  for (int a = 0; a < 2; ++a)
#pragma unroll
    for (int b = 0; b < 2; ++b) acc[a][b] = (f32x4){0.f, 0.f, 0.f, 0.f};

#pragma unroll
  for (int kk = 0; kk < 4; ++kk) {
    bf16x8 fa[2], fbv[2];
#pragma unroll
    for (int x = 0; x < 2; ++x)
      fa[x] = ((const bf16x8*)sAq)[kk * 512 + ((wri * 2 + x) << 6) + lane];
#pragma unroll
    for (int y = 0; y < 2; ++y)
      fbv[y] = ((const bf16x8*)sBq)[kk * 256 + ((wci * 2 + y) << 6) + lane];
#pragma unroll
    for (int tm = 0; tm < 2; ++tm)
#pragma unroll
      for (int tn = 0; tn < 2; ++tn)
        acc[tm][tn] =
            __builtin_amdgcn_mfma_f32_16x16x32_bf16(fa[tm], fbv[tn], acc[tm][tn], 0, 0, 0);
  }

  if ((tJc >> 1) == tI) {  // block touches the diagonal
    epilogue<true>(acc, liv, lj, dj, lane, wave, t, k, redA, redB, partials, counter,
                   &lastflag);
  } else {
    epilogue<false>(acc, liv, lj, dj, lane, wave, t, k, redA, redB, partials, counter,
                    &lastflag);
  }
  __syncthreads();
  if (!lastflag) return;

  // ---- last block: merge all partials (base-2), softplus, write out ----
  __threadfence();  // acquire: see other blocks' partials
  float Mp = -1e30f, Sp = 0.f, Mn = -1e30f, Sn = 0.f;
  for (int i = t; i < NBLOCKS; i += 512) {
    const float4 p = partials[i];
    lse_merge2(Mp, Sp, p.x, p.y);
    lse_merge2(Mn, Sn, p.z, p.w);
  }
#pragma unroll
  for (int o = 32; o > 0; o >>= 1) {
    const float am = __shfl_xor(Mp, o), as = __shfl_xor(Sp, o);
    lse_merge2(Mp, Sp, am, as);
    const float bm = __shfl_xor(Mn, o), bs = __shfl_xor(Sn, o);
    lse_merge2(Mn, Sn, bm, bs);
  }
  if (lane == 0) fred[wave] = make_float4(Mp, Sp, Mn, Sn);
  __syncthreads();
  if (t == 0) {
    float mpf = -1e30f, spf = 0.f, mnf = -1e30f, snf = 0.f;
#pragma unroll
    for (int w = 0; w < 8; ++w) {
      const float4 q = fred[w];
      lse_merge2(mpf, spf, q.x, q.y);
      lse_merge2(mnf, snf, q.z, q.w);
    }
    const float x = (mpf + mnf) * LN2 + logf(spf) + logf(snf);
    out[0] = fmaxf(x, 0.f) + log1pf(__expf(-fabsf(x)));  // stable softplus
  }
}

extern "C" void kernel_launch(void* const* d_in, const int* in_sizes, int n_in,
                              void* d_out, int out_size, void* d_ws, size_t ws_size,
                              hipStream_t stream) {
  const float* feat = (const float*)d_in[0];
  const int* labels = (const int*)d_in[1];
  float* out = (float*)d_out;

  unsigned short* fb = (unsigned short*)d_ws;  // 2 MB
  float4* partials = (float4*)((char*)d_ws + (size_t)N_PTS * DIM * 2);
  int* counter = (int*)((char*)d_ws + (size_t)N_PTS * DIM * 2 + NBLOCKS * sizeof(float4));

  normalize_kernel<<<N_PTS / 4, 256, 0, stream>>>(feat, fb, counter);
  pair_kernel<<<NBLOCKS, 512, 0, stream>>>(fb, labels, partials, counter, out);
}